// Round 12
// baseline (791.365 us; speedup 1.0000x reference)
//
#include <hip/hip_runtime.h>
#include <stdint.h>

#define L_LEN 512
#define D_DIM 4096
#define H_NUM 8
#define B_NUM 16
#define TOPK  12

typedef float f32x4 __attribute__((ext_vector_type(4)));

// ---------------------------------------------------------------------------
// Stage A — VERBATIM from round 8 (fastest passing: 499 us).
// grid = B*H*64 blocks of 256 threads = 4 waves; ONE channel per 32-lane
// half-wave. Lane m = lane&31 owns taus 16m..16m+15. Per 16-t step:
// 8 q b128 + 4 k b128 (half-wave-uniform broadcast) feed 256 FMAs.
// q LDS layout: 16B group G at phys G + (G>>3). Inline-asm ds_read_b128
// (hipcc scalarizes C-level float4 LDS reads; r4/r6 evidence).
// ---------------------------------------------------------------------------

#define QA(G) (qbase + (((((uint32_t)(G)) & 127u) + ((((uint32_t)(G)) & 127u) >> 3)) << 4))

#define MAC4x16(QA_, QB_, QC_, QD_, QE_, KK_) do {                            \
    acc0  = fmaf(QA_.x, KK_.x, acc0);  acc0  = fmaf(QA_.y, KK_.y, acc0);      \
    acc0  = fmaf(QA_.z, KK_.z, acc0);  acc0  = fmaf(QA_.w, KK_.w, acc0);      \
    acc1  = fmaf(QA_.y, KK_.x, acc1);  acc1  = fmaf(QA_.z, KK_.y, acc1);      \
    acc1  = fmaf(QA_.w, KK_.z, acc1);  acc1  = fmaf(QB_.x, KK_.w, acc1);      \
    acc2  = fmaf(QA_.z, KK_.x, acc2);  acc2  = fmaf(QA_.w, KK_.y, acc2);      \
    acc2  = fmaf(QB_.x, KK_.z, acc2);  acc2  = fmaf(QB_.y, KK_.w, acc2);      \
    acc3  = fmaf(QA_.w, KK_.x, acc3);  acc3  = fmaf(QB_.x, KK_.y, acc3);      \
    acc3  = fmaf(QB_.y, KK_.z, acc3);  acc3  = fmaf(QB_.z, KK_.w, acc3);      \
    acc4  = fmaf(QB_.x, KK_.x, acc4);  acc4  = fmaf(QB_.y, KK_.y, acc4);      \
    acc4  = fmaf(QB_.z, KK_.z, acc4);  acc4  = fmaf(QB_.w, KK_.w, acc4);      \
    acc5  = fmaf(QB_.y, KK_.x, acc5);  acc5  = fmaf(QB_.z, KK_.y, acc5);      \
    acc5  = fmaf(QB_.w, KK_.z, acc5);  acc5  = fmaf(QC_.x, KK_.w, acc5);      \
    acc6  = fmaf(QB_.z, KK_.x, acc6);  acc6  = fmaf(QB_.w, KK_.y, acc6);      \
    acc6  = fmaf(QC_.x, KK_.z, acc6);  acc6  = fmaf(QC_.y, KK_.w, acc6);      \
    acc7  = fmaf(QB_.w, KK_.x, acc7);  acc7  = fmaf(QC_.x, KK_.y, acc7);      \
    acc7  = fmaf(QC_.y, KK_.z, acc7);  acc7  = fmaf(QC_.z, KK_.w, acc7);      \
    acc8  = fmaf(QC_.x, KK_.x, acc8);  acc8  = fmaf(QC_.y, KK_.y, acc8);      \
    acc8  = fmaf(QC_.z, KK_.z, acc8);  acc8  = fmaf(QC_.w, KK_.w, acc8);      \
    acc9  = fmaf(QC_.y, KK_.x, acc9);  acc9  = fmaf(QC_.z, KK_.y, acc9);      \
    acc9  = fmaf(QC_.w, KK_.z, acc9);  acc9  = fmaf(QD_.x, KK_.w, acc9);      \
    acc10 = fmaf(QC_.z, KK_.x, acc10); acc10 = fmaf(QC_.w, KK_.y, acc10);     \
    acc10 = fmaf(QD_.x, KK_.z, acc10); acc10 = fmaf(QD_.y, KK_.w, acc10);     \
    acc11 = fmaf(QC_.w, KK_.x, acc11); acc11 = fmaf(QD_.x, KK_.y, acc11);     \
    acc11 = fmaf(QD_.y, KK_.z, acc11); acc11 = fmaf(QD_.z, KK_.w, acc11);     \
    acc12 = fmaf(QD_.x, KK_.x, acc12); acc12 = fmaf(QD_.y, KK_.y, acc12);     \
    acc12 = fmaf(QD_.z, KK_.z, acc12); acc12 = fmaf(QD_.w, KK_.w, acc12);     \
    acc13 = fmaf(QD_.y, KK_.x, acc13); acc13 = fmaf(QD_.z, KK_.y, acc13);     \
    acc13 = fmaf(QD_.w, KK_.z, acc13); acc13 = fmaf(QE_.x, KK_.w, acc13);     \
    acc14 = fmaf(QD_.z, KK_.x, acc14); acc14 = fmaf(QD_.w, KK_.y, acc14);     \
    acc14 = fmaf(QE_.x, KK_.z, acc14); acc14 = fmaf(QE_.y, KK_.w, acc14);     \
    acc15 = fmaf(QD_.w, KK_.x, acc15); acc15 = fmaf(QE_.x, KK_.y, acc15);     \
    acc15 = fmaf(QE_.y, KK_.z, acc15); acc15 = fmaf(QE_.z, KK_.w, acc15);     \
  } while (0)

#define ITERX(A0,A1,A2,A3, B0,B1,B2,B3, C0,C1,C2,C3) do {                    \
    const uint32_t a0_ = QA(gnext);                                          \
    const uint32_t a1_ = QA(gnext + 1);                                      \
    const uint32_t a2_ = QA(gnext + 2);                                      \
    const uint32_t a3_ = QA(gnext + 3);                                      \
    asm volatile(                                                            \
      "ds_read_b128 %0, %8\n\t"                                              \
      "ds_read_b128 %1, %9\n\t"                                              \
      "ds_read_b128 %2, %10\n\t"                                             \
      "ds_read_b128 %3, %11\n\t"                                             \
      "ds_read_b128 %4, %12\n\t"                                             \
      "ds_read_b128 %5, %12 offset:16\n\t"                                   \
      "ds_read_b128 %6, %12 offset:32\n\t"                                   \
      "ds_read_b128 %7, %12 offset:48\n\t"                                   \
      "s_waitcnt lgkmcnt(0)"                                                 \
      : "=&v"(C0), "=&v"(C1), "=&v"(C2), "=&v"(C3),                          \
        "=&v"(k0), "=&v"(k1), "=&v"(k2), "=&v"(k3)                           \
      : "v"(a0_), "v"(a1_), "v"(a2_), "v"(a3_), "v"(kptr)                    \
      : "memory");                                                           \
    MAC4x16(A0, A1, A2, A3, B0, k0);                                         \
    MAC4x16(A1, A2, A3, B0, B1, k1);                                         \
    MAC4x16(A2, A3, B0, B1, B2, k2);                                         \
    MAC4x16(A3, B0, B1, B2, B3, k3);                                         \
    gnext += 4; kptr += 64;                                                  \
  } while (0)

__global__ __launch_bounds__(256, 4) void corr_topk_kernel(
    const float* __restrict__ Q, const float* __restrict__ K,
    float* __restrict__ ws_w, int* __restrict__ ws_i)
{
  __shared__ __align__(16) float qs[8][576];   // 18432 B: 144 phys groups/row
  __shared__ __align__(16) float ks[8][512];   // 16384 B, linear (total 34816)

  const int tid = threadIdx.x;
  const int bid = blockIdx.x;
  const int work = (bid & 7) * 1024 + (bid >> 3);
  const int bh   = work >> 6;
  const int c0   = (work & 63) * 8;

  const size_t base = (size_t)(bh >> 3) * (size_t)(L_LEN * D_DIM)
                    + (size_t)(bh & 7) * 512 + c0;

  #pragma unroll
  for (int rep = 0; rep < 4; ++rep) {
    const int idx  = rep * 256 + tid;       // 0..1023
    const int t    = idx >> 1;
    const int half = idx & 1;
    const float4 qv = *(const float4*)(Q + base + (size_t)t * D_DIM + half * 4);
    const float4 kv = *(const float4*)(K + base + (size_t)t * D_DIM + half * 4);
    const int g  = t >> 2;
    const int pw = ((g + (g >> 3)) << 2) | (t & 3);
    const int cb = half * 4;
    const float qa[4] = {qv.x, qv.y, qv.z, qv.w};
    const float ka[4] = {kv.x, kv.y, kv.z, kv.w};
    #pragma unroll
    for (int j = 0; j < 4; ++j) {
      qs[cb + j][pw] = qa[j];
      ks[cb + j][t]  = ka[j];
    }
  }
  __syncthreads();

  const int wv   = tid >> 6;
  const int lane = tid & 63;
  const int m    = lane & 31;
  const int ch   = wv * 2 + (lane >> 5);
  const int tau0 = m * 16;
  const int gq   = m * 4;

  const uint32_t qbase = (uint32_t)(uintptr_t)(&qs[ch][0]);
  uint32_t       kptr  = (uint32_t)(uintptr_t)(&ks[ch][0]);

  float acc0  = 0.f, acc1  = 0.f, acc2  = 0.f, acc3  = 0.f;
  float acc4  = 0.f, acc5  = 0.f, acc6  = 0.f, acc7  = 0.f;
  float acc8  = 0.f, acc9  = 0.f, acc10 = 0.f, acc11 = 0.f;
  float acc12 = 0.f, acc13 = 0.f, acc14 = 0.f, acc15 = 0.f;
  f32x4 wA0, wA1, wA2, wA3, wB0, wB1, wB2, wB3, wC0, wC1, wC2, wC3;
  f32x4 k0, k1, k2, k3;

  {
    const uint32_t p0 = QA(gq),     p1 = QA(gq + 1);
    const uint32_t p2 = QA(gq + 2), p3 = QA(gq + 3);
    const uint32_t p4 = QA(gq + 4), p5 = QA(gq + 5);
    const uint32_t p6 = QA(gq + 6), p7 = QA(gq + 7);
    asm volatile(
      "ds_read_b128 %0, %8\n\t"
      "ds_read_b128 %1, %9\n\t"
      "ds_read_b128 %2, %10\n\t"
      "ds_read_b128 %3, %11\n\t"
      "ds_read_b128 %4, %12\n\t"
      "ds_read_b128 %5, %13\n\t"
      "ds_read_b128 %6, %14\n\t"
      "ds_read_b128 %7, %15\n\t"
      "s_waitcnt lgkmcnt(0)"
      : "=&v"(wA0), "=&v"(wA1), "=&v"(wA2), "=&v"(wA3),
        "=&v"(wB0), "=&v"(wB1), "=&v"(wB2), "=&v"(wB3)
      : "v"(p0), "v"(p1), "v"(p2), "v"(p3), "v"(p4), "v"(p5), "v"(p6), "v"(p7)
      : "memory");
  }

  uint32_t gnext = (uint32_t)(gq + 8);

  #pragma unroll 1
  for (int i = 0; i < 30; i += 3) {
    ITERX(wA0,wA1,wA2,wA3, wB0,wB1,wB2,wB3, wC0,wC1,wC2,wC3);
    ITERX(wB0,wB1,wB2,wB3, wC0,wC1,wC2,wC3, wA0,wA1,wA2,wA3);
    ITERX(wC0,wC1,wC2,wC3, wA0,wA1,wA2,wA3, wB0,wB1,wB2,wB3);
  }
  ITERX(wA0,wA1,wA2,wA3, wB0,wB1,wB2,wB3, wC0,wC1,wC2,wC3);  // step 30
  ITERX(wB0,wB1,wB2,wB3, wC0,wC1,wC2,wC3, wA0,wA1,wA2,wA3);  // step 31 (tail junk unused)

  float acc[16] = {acc0, acc1, acc2,  acc3,  acc4,  acc5,  acc6,  acc7,
                   acc8, acc9, acc10, acc11, acc12, acc13, acc14, acc15};

  float bv[TOPK]; int bi[TOPK];
  #pragma unroll
  for (int s = 0; s < TOPK; ++s) {
    float lv = acc[0]; int li = 0;
    #pragma unroll
    for (int i = 1; i < 16; ++i) if (acc[i] > lv) { lv = acc[i]; li = i; }
    int gi = tau0 + li;
    #pragma unroll
    for (int off = 16; off >= 1; off >>= 1) {
      const float ov = __shfl_xor(lv, off, 32);
      const int   oi = __shfl_xor(gi, off, 32);
      if (ov > lv || (ov == lv && oi < gi)) { lv = ov; gi = oi; }
    }
    bv[s] = lv; bi[s] = gi;
    const int slot = gi - tau0;
    #pragma unroll
    for (int i = 0; i < 16; ++i) acc[i] = (slot == i) ? -3.4e38f : acc[i];
  }

  float e[TOPK]; float sum = 0.f;
  #pragma unroll
  for (int s = 0; s < TOPK; ++s) { e[s] = expf(bv[s] - bv[0]); sum += e[s]; }
  const float inv = 1.f / sum;

  if (m == 0) {
    const int g = (bh * 512 + c0 + ch) * TOPK;
    #pragma unroll
    for (int s = 0; s < TOPK; ++s) { ws_w[g + s] = e[s] * inv; ws_i[g + s] = bi[s]; }
  }
}

// ---------------------------------------------------------------------------
// Stage B — 16-column tiles for 2x occupancy (r10 audit: 64 KB tile =
// 2 blocks/CU = 4 waves/SIMD, ~8% issue util, latency-starved).
// vs[512][16] = 32768 B -> 4 blocks/CU x 8 waves = 8 waves/SIMD.
// grid = 16 b * 256 dg = 4096 blocks of 512 threads  (r11 crash was a
// stale H_NUM factor in the LAUNCH line: 32768 blocks -> b up to 29 ->
// OOB vcol -> memory fault. Kernel body unchanged.)
// Descending quarters (r = min(r0+t,511) >= t: later stagings write
// strictly lower rows than any concurrent reader; 1 raw s_barrier/phase;
// next quarter's loads issued before the barrier stay in VMEM flight).
// Gather banks: lanes sharing cl have consecutive t -> bank =
// cl + 16*(r&1) -> 2 lanes/bank = free; clamped lanes broadcast.
// ---------------------------------------------------------------------------
__global__ __launch_bounds__(512, 8) void gather_kernel(
    const float* __restrict__ V, const float* __restrict__ ws_w,
    const int* __restrict__ ws_i, float* __restrict__ out)
{
  __shared__ __align__(16) float vs[512][16];   // 32768 B

  const int tid = threadIdx.x;
  const int bid = blockIdx.x;
  const int work = (bid & 7) * 512 + (bid >> 3);   // chunked XCD remap, 4096=8*512
  const int b  = work >> 8;
  const int dg = work & 255;
  const int d0 = dg * 16;
  const int h  = d0 >> 9;
  const int c0 = d0 & 511;

  const size_t vcol = (size_t)b * (size_t)(L_LEN * D_DIM) + d0;

  const int cl   = tid & 15;
  const int tsub = tid >> 4;              // 0..31

  const int ra = tid >> 2;                // row 0..127 within quarter
  const int qa = (tid & 3) * 4;           // 0,4,8,12

  float4 stga;
  // prologue: issue load for phase 3 (rows 384..511)
  stga = *(const float4*)(V + vcol + (size_t)(384 + ra) * D_DIM + qa);

  const int g = ((b * 8 + h) * 512 + c0 + cl) * TOPK;
  float w[TOPK]; int r0[TOPK];
  #pragma unroll
  for (int s = 0; s < TOPK; ++s) { w[s] = ws_w[g + s]; r0[s] = ws_i[g + s]; }

  const size_t ob = vcol + cl;

  #pragma unroll 1
  for (int ph = 3; ph >= 0; --ph) {
    *(float4*)(&vs[ph * 128 + ra][qa]) = stga;   // vmcnt wait auto-inserted
    if (ph > 0) {  // issue next quarter early; in flight across the barrier
      stga = *(const float4*)(V + vcol + (size_t)((ph - 1) * 128 + ra) * D_DIM + qa);
    }
    asm volatile("s_waitcnt lgkmcnt(0)" ::: "memory");
    __builtin_amdgcn_s_barrier();
    asm volatile("" ::: "memory");

    // outputs t in [ph*128, (ph+1)*128): 4 per thread
    #pragma unroll
    for (int j = 0; j < 4; ++j) {
      const int t = ph * 128 + j * 32 + tsub;
      float a = 0.f;
      #pragma unroll
      for (int s = 0; s < TOPK; ++s) {
        int r = r0[s] + t;
        r = r > (L_LEN - 1) ? (L_LEN - 1) : r;
        a = fmaf(w[s], vs[r][cl], a);
      }
      out[ob + (size_t)t * D_DIM] = a;
    }
  }
}

extern "C" void kernel_launch(void* const* d_in, const int* in_sizes, int n_in,
                              void* d_out, int out_size, void* d_ws, size_t ws_size,
                              hipStream_t stream)
{
  const float* Q = (const float*)d_in[0];
  const float* K = (const float*)d_in[1];
  const float* V = (const float*)d_in[2];
  float* out = (float*)d_out;

  float* ws_w = (float*)d_ws;
  int*   ws_i = (int*)((char*)d_ws + (size_t)B_NUM * H_NUM * 512 * TOPK * sizeof(float));

  corr_topk_kernel<<<dim3(B_NUM * H_NUM * 64), dim3(256), 0, stream>>>(Q, K, ws_w, ws_i);
  gather_kernel<<<dim3(B_NUM * 256), dim3(512), 0, stream>>>(V, ws_w, ws_i, out);
}

// Round 13
// 768.427 us; speedup vs baseline: 1.0299x; 1.0299x over previous
//
#include <hip/hip_runtime.h>
#include <stdint.h>

#define L_LEN 512
#define D_DIM 4096
#define H_NUM 8
#define B_NUM 16
#define TOPK  12

typedef float f32x4 __attribute__((ext_vector_type(4)));

// ---------------------------------------------------------------------------
// Stage A — r8 structure; q layout switched from additive pad (34816 B) to
// XOR group swizzle (zero pad): phys group = g ^ (((g>>3)&3)<<1), bijective
// on [0,128). LDS = 8*(512+512)*4 = 32768 B exactly -> 5 blocks/CU (was 4),
// +25% waves. Read cohorts (8 consecutive lanes, G step 4) now cover 4
// bank-groups x 2 lanes (distinct addrs) = 2-way = free (m136).
// Lane m = lane&31 owns taus 16m..16m+15; one channel per half-wave;
// k reads half-wave-uniform broadcast. Inline-asm ds_read_b128 throughout
// (hipcc scalarizes C-level float4 LDS reads; r4/r6 evidence).
// ---------------------------------------------------------------------------

#define QA(G) (qbase + (((((G) & 127u) ^ (((((G) & 127u) >> 3) & 3u) << 1)) << 4)))

#define MAC4x16(QA_, QB_, QC_, QD_, QE_, KK_) do {                            \
    acc0  = fmaf(QA_.x, KK_.x, acc0);  acc0  = fmaf(QA_.y, KK_.y, acc0);      \
    acc0  = fmaf(QA_.z, KK_.z, acc0);  acc0  = fmaf(QA_.w, KK_.w, acc0);      \
    acc1  = fmaf(QA_.y, KK_.x, acc1);  acc1  = fmaf(QA_.z, KK_.y, acc1);      \
    acc1  = fmaf(QA_.w, KK_.z, acc1);  acc1  = fmaf(QB_.x, KK_.w, acc1);      \
    acc2  = fmaf(QA_.z, KK_.x, acc2);  acc2  = fmaf(QA_.w, KK_.y, acc2);      \
    acc2  = fmaf(QB_.x, KK_.z, acc2);  acc2  = fmaf(QB_.y, KK_.w, acc2);      \
    acc3  = fmaf(QA_.w, KK_.x, acc3);  acc3  = fmaf(QB_.x, KK_.y, acc3);      \
    acc3  = fmaf(QB_.y, KK_.z, acc3);  acc3  = fmaf(QB_.z, KK_.w, acc3);      \
    acc4  = fmaf(QB_.x, KK_.x, acc4);  acc4  = fmaf(QB_.y, KK_.y, acc4);      \
    acc4  = fmaf(QB_.z, KK_.z, acc4);  acc4  = fmaf(QB_.w, KK_.w, acc4);      \
    acc5  = fmaf(QB_.y, KK_.x, acc5);  acc5  = fmaf(QB_.z, KK_.y, acc5);      \
    acc5  = fmaf(QB_.w, KK_.z, acc5);  acc5  = fmaf(QC_.x, KK_.w, acc5);      \
    acc6  = fmaf(QB_.z, KK_.x, acc6);  acc6  = fmaf(QB_.w, KK_.y, acc6);      \
    acc6  = fmaf(QC_.x, KK_.z, acc6);  acc6  = fmaf(QC_.y, KK_.w, acc6);      \
    acc7  = fmaf(QB_.w, KK_.x, acc7);  acc7  = fmaf(QC_.x, KK_.y, acc7);      \
    acc7  = fmaf(QC_.y, KK_.z, acc7);  acc7  = fmaf(QC_.z, KK_.w, acc7);      \
    acc8  = fmaf(QC_.x, KK_.x, acc8);  acc8  = fmaf(QC_.y, KK_.y, acc8);      \
    acc8  = fmaf(QC_.z, KK_.z, acc8);  acc8  = fmaf(QC_.w, KK_.w, acc8);      \
    acc9  = fmaf(QC_.y, KK_.x, acc9);  acc9  = fmaf(QC_.z, KK_.y, acc9);      \
    acc9  = fmaf(QC_.w, KK_.z, acc9);  acc9  = fmaf(QD_.x, KK_.w, acc9);      \
    acc10 = fmaf(QC_.z, KK_.x, acc10); acc10 = fmaf(QC_.w, KK_.y, acc10);     \
    acc10 = fmaf(QD_.x, KK_.z, acc10); acc10 = fmaf(QD_.y, KK_.w, acc10);     \
    acc11 = fmaf(QC_.w, KK_.x, acc11); acc11 = fmaf(QD_.x, KK_.y, acc11);     \
    acc11 = fmaf(QD_.y, KK_.z, acc11); acc11 = fmaf(QD_.z, KK_.w, acc11);     \
    acc12 = fmaf(QD_.x, KK_.x, acc12); acc12 = fmaf(QD_.y, KK_.y, acc12);     \
    acc12 = fmaf(QD_.z, KK_.z, acc12); acc12 = fmaf(QD_.w, KK_.w, acc12);     \
    acc13 = fmaf(QD_.y, KK_.x, acc13); acc13 = fmaf(QD_.z, KK_.y, acc13);     \
    acc13 = fmaf(QD_.w, KK_.z, acc13); acc13 = fmaf(QE_.x, KK_.w, acc13);     \
    acc14 = fmaf(QD_.z, KK_.x, acc14); acc14 = fmaf(QD_.w, KK_.y, acc14);     \
    acc14 = fmaf(QE_.x, KK_.z, acc14); acc14 = fmaf(QE_.y, KK_.w, acc14);     \
    acc15 = fmaf(QD_.w, KK_.x, acc15); acc15 = fmaf(QE_.x, KK_.y, acc15);     \
    acc15 = fmaf(QE_.y, KK_.z, acc15); acc15 = fmaf(QE_.z, KK_.w, acc15);     \
  } while (0)

#define ITERX(A0,A1,A2,A3, B0,B1,B2,B3, C0,C1,C2,C3) do {                    \
    const uint32_t a0_ = QA(gnext);                                          \
    const uint32_t a1_ = QA(gnext + 1);                                      \
    const uint32_t a2_ = QA(gnext + 2);                                      \
    const uint32_t a3_ = QA(gnext + 3);                                      \
    asm volatile(                                                            \
      "ds_read_b128 %0, %8\n\t"                                              \
      "ds_read_b128 %1, %9\n\t"                                              \
      "ds_read_b128 %2, %10\n\t"                                             \
      "ds_read_b128 %3, %11\n\t"                                             \
      "ds_read_b128 %4, %12\n\t"                                             \
      "ds_read_b128 %5, %12 offset:16\n\t"                                   \
      "ds_read_b128 %6, %12 offset:32\n\t"                                   \
      "ds_read_b128 %7, %12 offset:48\n\t"                                   \
      "s_waitcnt lgkmcnt(0)"                                                 \
      : "=&v"(C0), "=&v"(C1), "=&v"(C2), "=&v"(C3),                          \
        "=&v"(k0), "=&v"(k1), "=&v"(k2), "=&v"(k3)                           \
      : "v"(a0_), "v"(a1_), "v"(a2_), "v"(a3_), "v"(kptr)                    \
      : "memory");                                                           \
    MAC4x16(A0, A1, A2, A3, B0, k0);                                         \
    MAC4x16(A1, A2, A3, B0, B1, k1);                                         \
    MAC4x16(A2, A3, B0, B1, B2, k2);                                         \
    MAC4x16(A3, B0, B1, B2, B3, k3);                                         \
    gnext += 4; kptr += 64;                                                  \
  } while (0)

__global__ __launch_bounds__(256, 4) void corr_topk_kernel(
    const float* __restrict__ Q, const float* __restrict__ K,
    float* __restrict__ ws_w, int* __restrict__ ws_i)
{
  __shared__ __align__(16) float qs[8][512];   // 16384 B, XOR group swizzle
  __shared__ __align__(16) float ks[8][512];   // 16384 B, linear (total 32768)

  const int tid = threadIdx.x;
  const int bid = blockIdx.x;
  const int work = (bid & 7) * 1024 + (bid >> 3);
  const int bh   = work >> 6;
  const int c0   = (work & 63) * 8;

  const size_t base = (size_t)(bh >> 3) * (size_t)(L_LEN * D_DIM)
                    + (size_t)(bh & 7) * 512 + c0;

  #pragma unroll
  for (int rep = 0; rep < 4; ++rep) {
    const int idx  = rep * 256 + tid;       // 0..1023
    const int t    = idx >> 1;
    const int half = idx & 1;
    const float4 qv = *(const float4*)(Q + base + (size_t)t * D_DIM + half * 4);
    const float4 kv = *(const float4*)(K + base + (size_t)t * D_DIM + half * 4);
    const int g  = t >> 2;
    const int pg = g ^ (((g >> 3) & 3) << 1);          // XOR swizzle
    const int pw = (pg << 2) | (t & 3);
    const int cb = half * 4;
    const float qa[4] = {qv.x, qv.y, qv.z, qv.w};
    const float ka[4] = {kv.x, kv.y, kv.z, kv.w};
    #pragma unroll
    for (int j = 0; j < 4; ++j) {
      qs[cb + j][pw] = qa[j];
      ks[cb + j][t]  = ka[j];
    }
  }
  __syncthreads();

  const int wv   = tid >> 6;
  const int lane = tid & 63;
  const int m    = lane & 31;
  const int ch   = wv * 2 + (lane >> 5);
  const int tau0 = m * 16;
  const uint32_t gq = (uint32_t)(m * 4);

  const uint32_t qbase = (uint32_t)(uintptr_t)(&qs[ch][0]);
  uint32_t       kptr  = (uint32_t)(uintptr_t)(&ks[ch][0]);

  float acc0  = 0.f, acc1  = 0.f, acc2  = 0.f, acc3  = 0.f;
  float acc4  = 0.f, acc5  = 0.f, acc6  = 0.f, acc7  = 0.f;
  float acc8  = 0.f, acc9  = 0.f, acc10 = 0.f, acc11 = 0.f;
  float acc12 = 0.f, acc13 = 0.f, acc14 = 0.f, acc15 = 0.f;
  f32x4 wA0, wA1, wA2, wA3, wB0, wB1, wB2, wB3, wC0, wC1, wC2, wC3;
  f32x4 k0, k1, k2, k3;

  {
    const uint32_t p0 = QA(gq),     p1 = QA(gq + 1);
    const uint32_t p2 = QA(gq + 2), p3 = QA(gq + 3);
    const uint32_t p4 = QA(gq + 4), p5 = QA(gq + 5);
    const uint32_t p6 = QA(gq + 6), p7 = QA(gq + 7);
    asm volatile(
      "ds_read_b128 %0, %8\n\t"
      "ds_read_b128 %1, %9\n\t"
      "ds_read_b128 %2, %10\n\t"
      "ds_read_b128 %3, %11\n\t"
      "ds_read_b128 %4, %12\n\t"
      "ds_read_b128 %5, %13\n\t"
      "ds_read_b128 %6, %14\n\t"
      "ds_read_b128 %7, %15\n\t"
      "s_waitcnt lgkmcnt(0)"
      : "=&v"(wA0), "=&v"(wA1), "=&v"(wA2), "=&v"(wA3),
        "=&v"(wB0), "=&v"(wB1), "=&v"(wB2), "=&v"(wB3)
      : "v"(p0), "v"(p1), "v"(p2), "v"(p3), "v"(p4), "v"(p5), "v"(p6), "v"(p7)
      : "memory");
  }

  uint32_t gnext = gq + 8;

  #pragma unroll 1
  for (int i = 0; i < 30; i += 3) {
    ITERX(wA0,wA1,wA2,wA3, wB0,wB1,wB2,wB3, wC0,wC1,wC2,wC3);
    ITERX(wB0,wB1,wB2,wB3, wC0,wC1,wC2,wC3, wA0,wA1,wA2,wA3);
    ITERX(wC0,wC1,wC2,wC3, wA0,wA1,wA2,wA3, wB0,wB1,wB2,wB3);
  }
  ITERX(wA0,wA1,wA2,wA3, wB0,wB1,wB2,wB3, wC0,wC1,wC2,wC3);  // step 30
  ITERX(wB0,wB1,wB2,wB3, wC0,wC1,wC2,wC3, wA0,wA1,wA2,wA3);  // step 31 (tail junk unused)

  float acc[16] = {acc0, acc1, acc2,  acc3,  acc4,  acc5,  acc6,  acc7,
                   acc8, acc9, acc10, acc11, acc12, acc13, acc14, acc15};

  float bv[TOPK]; int bi[TOPK];
  #pragma unroll
  for (int s = 0; s < TOPK; ++s) {
    float lv = acc[0]; int li = 0;
    #pragma unroll
    for (int i = 1; i < 16; ++i) if (acc[i] > lv) { lv = acc[i]; li = i; }
    int gi = tau0 + li;
    #pragma unroll
    for (int off = 16; off >= 1; off >>= 1) {
      const float ov = __shfl_xor(lv, off, 32);
      const int   oi = __shfl_xor(gi, off, 32);
      if (ov > lv || (ov == lv && oi < gi)) { lv = ov; gi = oi; }
    }
    bv[s] = lv; bi[s] = gi;
    const int slot = gi - tau0;
    #pragma unroll
    for (int i = 0; i < 16; ++i) acc[i] = (slot == i) ? -3.4e38f : acc[i];
  }

  float e[TOPK]; float sum = 0.f;
  #pragma unroll
  for (int s = 0; s < TOPK; ++s) { e[s] = expf(bv[s] - bv[0]); sum += e[s]; }
  const float inv = 1.f / sum;

  if (m == 0) {
    const int g = (bh * 512 + c0 + ch) * TOPK;
    #pragma unroll
    for (int s = 0; s < TOPK; ++s) { ws_w[g + s] = e[s] * inv; ws_i[g + s] = bi[s]; }
  }
}

// ---------------------------------------------------------------------------
// Stage B — VERBATIM round-8 passing version (best measured total).
// block = (b, 32-column window of D), 512 threads, vs[512][32] = 65536 B,
// descending quarters (r = min(r0+t,511) >= t -> later stagings write
// strictly lower rows than any concurrent reader; 1 raw s_barrier/phase;
// next quarter's loads issued before the barrier stay in VMEM flight).
// grid = 16*8*16 = 2048 blocks.
// ---------------------------------------------------------------------------
__global__ __launch_bounds__(512, 4) void gather_kernel(
    const float* __restrict__ V, const float* __restrict__ ws_w,
    const int* __restrict__ ws_i, float* __restrict__ out)
{
  __shared__ __align__(16) float vs[512][32];   // 65536 B

  const int tid = threadIdx.x;
  const int bid = blockIdx.x;
  const int work = (bid & 7) * 256 + (bid >> 3);   // chunked XCD remap
  const int b  = work >> 7;
  const int dg = work & 127;
  const int d0 = dg * 32;
  const int h  = d0 >> 9;
  const int c0 = d0 & 511;

  const size_t vcol = (size_t)b * (size_t)(L_LEN * D_DIM) + d0;

  const int cl   = tid & 31;
  const int tsub = tid >> 5;              // 0..15

  float4 stga, stgb;
  const int e0 = tid, e1 = 512 + tid;
  const int ra0 = e0 >> 3, qa0 = (e0 & 7) * 4;   // rows 0..63 of quarter
  const int rb0 = e1 >> 3, qb0 = (e1 & 7) * 4;   // rows 64..127 of quarter

  // prologue: issue loads for phase 3 (rows 384..511)
  stga = *(const float4*)(V + vcol + (size_t)(384 + ra0) * D_DIM + qa0);
  stgb = *(const float4*)(V + vcol + (size_t)(384 + rb0) * D_DIM + qb0);

  const int g = ((b * 8 + h) * 512 + c0 + cl) * TOPK;
  float w[TOPK]; int r0[TOPK];
  #pragma unroll
  for (int s = 0; s < TOPK; ++s) { w[s] = ws_w[g + s]; r0[s] = ws_i[g + s]; }

  const size_t ob = vcol + cl;

  #pragma unroll 1
  for (int ph = 3; ph >= 0; --ph) {
    *(float4*)(&vs[ph * 128 + ra0][qa0]) = stga;
    *(float4*)(&vs[ph * 128 + rb0][qb0]) = stgb;
    if (ph > 0) {  // issue next quarter early; in flight across the barrier
      stga = *(const float4*)(V + vcol + (size_t)((ph - 1) * 128 + ra0) * D_DIM + qa0);
      stgb = *(const float4*)(V + vcol + (size_t)((ph - 1) * 128 + rb0) * D_DIM + qb0);
    }
    asm volatile("s_waitcnt lgkmcnt(0)" ::: "memory");
    __builtin_amdgcn_s_barrier();
    asm volatile("" ::: "memory");

    // compute outputs t in [ph*128, (ph+1)*128)
    #pragma unroll
    for (int k8 = 0; k8 < 8; ++k8) {
      const int t = ph * 128 + (k8 << 4) + tsub;
      float a = 0.f;
      #pragma unroll
      for (int s = 0; s < TOPK; ++s) {
        int r = r0[s] + t;
        r = r > (L_LEN - 1) ? (L_LEN - 1) : r;
        a = fmaf(w[s], vs[r][cl], a);       // bank = cl: scatter-immune
      }
      out[ob + (size_t)t * D_DIM] = a;
    }
  }
}

extern "C" void kernel_launch(void* const* d_in, const int* in_sizes, int n_in,
                              void* d_out, int out_size, void* d_ws, size_t ws_size,
                              hipStream_t stream)
{
  const float* Q = (const float*)d_in[0];
  const float* K = (const float*)d_in[1];
  const float* V = (const float*)d_in[2];
  float* out = (float*)d_out;

  float* ws_w = (float*)d_ws;
  int*   ws_i = (int*)((char*)d_ws + (size_t)B_NUM * H_NUM * 512 * TOPK * sizeof(float));

  corr_topk_kernel<<<dim3(B_NUM * H_NUM * 64), dim3(256), 0, stream>>>(Q, K, ws_w, ws_i);
  gather_kernel<<<dim3(B_NUM * H_NUM * 16), dim3(512), 0, stream>>>(V, ws_w, ws_i, out);
}

// Round 14
// 736.844 us; speedup vs baseline: 1.0740x; 1.0429x over previous
//
#include <hip/hip_runtime.h>
#include <stdint.h>

#define L_LEN 512
#define D_DIM 4096
#define H_NUM 8
#define B_NUM 16
#define TOPK  12

typedef float f32x4 __attribute__((ext_vector_type(4)));

// ---------------------------------------------------------------------------
// Stage A — 32 taus/lane (halved LDS-read density vs r8; r13 post-mortem:
// conflicts/occupancy/latency all proven non-levers, read count is).
// grid = B*H*64 blocks of 128 threads = 2 waves; 8 channels/block, ONE
// channel per 16 lanes. Lane m = lane&15 owns taus 32m..32m+31.
// Per 16-t step: 4 q b128 + 4 k b128 -> 512 FMAs (was 8 reads / 256).
// Window = 16 named quads in 4 banks (period-4 rotation), 12 live in MACs.
// Single asm block per step {reads -> drain -> MAC}: r8-proven, spill-safe.
// q layout: additive pad, phys group = g + (g>>3) (r8-proven, low-conflict).
// ---------------------------------------------------------------------------

#define QA(G) (qbase + (((((uint32_t)(G)) & 127u) + ((((uint32_t)(G)) & 127u) >> 3)) << 4))

// accs 0-15 (taus tau0..tau0+15): acc_i += q[i+t]*k[t], t=0..3 of KK_
#define MACLO(QA_, QB_, QC_, QD_, QE_, KK_) do {                              \
    acc0  = fmaf(QA_.x, KK_.x, acc0);  acc0  = fmaf(QA_.y, KK_.y, acc0);      \
    acc0  = fmaf(QA_.z, KK_.z, acc0);  acc0  = fmaf(QA_.w, KK_.w, acc0);      \
    acc1  = fmaf(QA_.y, KK_.x, acc1);  acc1  = fmaf(QA_.z, KK_.y, acc1);      \
    acc1  = fmaf(QA_.w, KK_.z, acc1);  acc1  = fmaf(QB_.x, KK_.w, acc1);      \
    acc2  = fmaf(QA_.z, KK_.x, acc2);  acc2  = fmaf(QA_.w, KK_.y, acc2);      \
    acc2  = fmaf(QB_.x, KK_.z, acc2);  acc2  = fmaf(QB_.y, KK_.w, acc2);      \
    acc3  = fmaf(QA_.w, KK_.x, acc3);  acc3  = fmaf(QB_.x, KK_.y, acc3);      \
    acc3  = fmaf(QB_.y, KK_.z, acc3);  acc3  = fmaf(QB_.z, KK_.w, acc3);      \
    acc4  = fmaf(QB_.x, KK_.x, acc4);  acc4  = fmaf(QB_.y, KK_.y, acc4);      \
    acc4  = fmaf(QB_.z, KK_.z, acc4);  acc4  = fmaf(QB_.w, KK_.w, acc4);      \
    acc5  = fmaf(QB_.y, KK_.x, acc5);  acc5  = fmaf(QB_.z, KK_.y, acc5);      \
    acc5  = fmaf(QB_.w, KK_.z, acc5);  acc5  = fmaf(QC_.x, KK_.w, acc5);      \
    acc6  = fmaf(QB_.z, KK_.x, acc6);  acc6  = fmaf(QB_.w, KK_.y, acc6);      \
    acc6  = fmaf(QC_.x, KK_.z, acc6);  acc6  = fmaf(QC_.y, KK_.w, acc6);      \
    acc7  = fmaf(QB_.w, KK_.x, acc7);  acc7  = fmaf(QC_.x, KK_.y, acc7);      \
    acc7  = fmaf(QC_.y, KK_.z, acc7);  acc7  = fmaf(QC_.z, KK_.w, acc7);      \
    acc8  = fmaf(QC_.x, KK_.x, acc8);  acc8  = fmaf(QC_.y, KK_.y, acc8);      \
    acc8  = fmaf(QC_.z, KK_.z, acc8);  acc8  = fmaf(QC_.w, KK_.w, acc8);      \
    acc9  = fmaf(QC_.y, KK_.x, acc9);  acc9  = fmaf(QC_.z, KK_.y, acc9);      \
    acc9  = fmaf(QC_.w, KK_.z, acc9);  acc9  = fmaf(QD_.x, KK_.w, acc9);      \
    acc10 = fmaf(QC_.z, KK_.x, acc10); acc10 = fmaf(QC_.w, KK_.y, acc10);     \
    acc10 = fmaf(QD_.x, KK_.z, acc10); acc10 = fmaf(QD_.y, KK_.w, acc10);     \
    acc11 = fmaf(QC_.w, KK_.x, acc11); acc11 = fmaf(QD_.x, KK_.y, acc11);     \
    acc11 = fmaf(QD_.y, KK_.z, acc11); acc11 = fmaf(QD_.z, KK_.w, acc11);     \
    acc12 = fmaf(QD_.x, KK_.x, acc12); acc12 = fmaf(QD_.y, KK_.y, acc12);     \
    acc12 = fmaf(QD_.z, KK_.z, acc12); acc12 = fmaf(QD_.w, KK_.w, acc12);     \
    acc13 = fmaf(QD_.y, KK_.x, acc13); acc13 = fmaf(QD_.z, KK_.y, acc13);     \
    acc13 = fmaf(QD_.w, KK_.z, acc13); acc13 = fmaf(QE_.x, KK_.w, acc13);     \
    acc14 = fmaf(QD_.z, KK_.x, acc14); acc14 = fmaf(QD_.w, KK_.y, acc14);     \
    acc14 = fmaf(QE_.x, KK_.z, acc14); acc14 = fmaf(QE_.y, KK_.w, acc14);     \
    acc15 = fmaf(QD_.w, KK_.x, acc15); acc15 = fmaf(QE_.x, KK_.y, acc15);     \
    acc15 = fmaf(QE_.y, KK_.z, acc15); acc15 = fmaf(QE_.z, KK_.w, acc15);     \
  } while (0)

// accs 16-31 (taus tau0+16..tau0+31): same shape, window shifted 4 quads
#define MACHI(QA_, QB_, QC_, QD_, QE_, KK_) do {                              \
    acc16 = fmaf(QA_.x, KK_.x, acc16); acc16 = fmaf(QA_.y, KK_.y, acc16);     \
    acc16 = fmaf(QA_.z, KK_.z, acc16); acc16 = fmaf(QA_.w, KK_.w, acc16);     \
    acc17 = fmaf(QA_.y, KK_.x, acc17); acc17 = fmaf(QA_.z, KK_.y, acc17);     \
    acc17 = fmaf(QA_.w, KK_.z, acc17); acc17 = fmaf(QB_.x, KK_.w, acc17);     \
    acc18 = fmaf(QA_.z, KK_.x, acc18); acc18 = fmaf(QA_.w, KK_.y, acc18);     \
    acc18 = fmaf(QB_.x, KK_.z, acc18); acc18 = fmaf(QB_.y, KK_.w, acc18);     \
    acc19 = fmaf(QA_.w, KK_.x, acc19); acc19 = fmaf(QB_.x, KK_.y, acc19);     \
    acc19 = fmaf(QB_.y, KK_.z, acc19); acc19 = fmaf(QB_.z, KK_.w, acc19);     \
    acc20 = fmaf(QB_.x, KK_.x, acc20); acc20 = fmaf(QB_.y, KK_.y, acc20);     \
    acc20 = fmaf(QB_.z, KK_.z, acc20); acc20 = fmaf(QB_.w, KK_.w, acc20);     \
    acc21 = fmaf(QB_.y, KK_.x, acc21); acc21 = fmaf(QB_.z, KK_.y, acc21);     \
    acc21 = fmaf(QB_.w, KK_.z, acc21); acc21 = fmaf(QC_.x, KK_.w, acc21);     \
    acc22 = fmaf(QB_.z, KK_.x, acc22); acc22 = fmaf(QB_.w, KK_.y, acc22);     \
    acc22 = fmaf(QC_.x, KK_.z, acc22); acc22 = fmaf(QC_.y, KK_.w, acc22);     \
    acc23 = fmaf(QB_.w, KK_.x, acc23); acc23 = fmaf(QC_.x, KK_.y, acc23);     \
    acc23 = fmaf(QC_.y, KK_.z, acc23); acc23 = fmaf(QC_.z, KK_.w, acc23);     \
    acc24 = fmaf(QC_.x, KK_.x, acc24); acc24 = fmaf(QC_.y, KK_.y, acc24);     \
    acc24 = fmaf(QC_.z, KK_.z, acc24); acc24 = fmaf(QC_.w, KK_.w, acc24);     \
    acc25 = fmaf(QC_.y, KK_.x, acc25); acc25 = fmaf(QC_.z, KK_.y, acc25);     \
    acc25 = fmaf(QC_.w, KK_.z, acc25); acc25 = fmaf(QD_.x, KK_.w, acc25);     \
    acc26 = fmaf(QC_.z, KK_.x, acc26); acc26 = fmaf(QC_.w, KK_.y, acc26);     \
    acc26 = fmaf(QD_.x, KK_.z, acc26); acc26 = fmaf(QD_.y, KK_.w, acc26);     \
    acc27 = fmaf(QC_.w, KK_.x, acc27); acc27 = fmaf(QD_.x, KK_.y, acc27);     \
    acc27 = fmaf(QD_.y, KK_.z, acc27); acc27 = fmaf(QD_.z, KK_.w, acc27);     \
    acc28 = fmaf(QD_.x, KK_.x, acc28); acc28 = fmaf(QD_.y, KK_.y, acc28);     \
    acc28 = fmaf(QD_.z, KK_.z, acc28); acc28 = fmaf(QD_.w, KK_.w, acc28);     \
    acc29 = fmaf(QD_.y, KK_.x, acc29); acc29 = fmaf(QD_.z, KK_.y, acc29);     \
    acc29 = fmaf(QD_.w, KK_.z, acc29); acc29 = fmaf(QE_.x, KK_.w, acc29);     \
    acc30 = fmaf(QD_.z, KK_.x, acc30); acc30 = fmaf(QD_.w, KK_.y, acc30);     \
    acc30 = fmaf(QE_.x, KK_.z, acc30); acc30 = fmaf(QE_.y, KK_.w, acc30);     \
    acc31 = fmaf(QD_.w, KK_.x, acc31); acc31 = fmaf(QE_.x, KK_.y, acc31);     \
    acc31 = fmaf(QE_.y, KK_.z, acc31); acc31 = fmaf(QE_.z, KK_.w, acc31);     \
  } while (0)

// One 16-t step. L0..L11 = live window quads (logical order), X0..X3 = bank
// being refilled (next step's 4 quads). 8 reads + drain + 512 FMAs.
#define ITER32(L0,L1,L2,L3,L4,L5,L6,L7,L8,L9,L10,L11, X0,X1,X2,X3) do {       \
    const uint32_t a0_ = QA(gnext);                                           \
    const uint32_t a1_ = QA(gnext + 1);                                       \
    const uint32_t a2_ = QA(gnext + 2);                                       \
    const uint32_t a3_ = QA(gnext + 3);                                       \
    asm volatile(                                                             \
      "ds_read_b128 %0, %8\n\t"                                               \
      "ds_read_b128 %1, %9\n\t"                                               \
      "ds_read_b128 %2, %10\n\t"                                              \
      "ds_read_b128 %3, %11\n\t"                                              \
      "ds_read_b128 %4, %12\n\t"                                              \
      "ds_read_b128 %5, %12 offset:16\n\t"                                    \
      "ds_read_b128 %6, %12 offset:32\n\t"                                    \
      "ds_read_b128 %7, %12 offset:48\n\t"                                    \
      "s_waitcnt lgkmcnt(0)"                                                  \
      : "=&v"(X0), "=&v"(X1), "=&v"(X2), "=&v"(X3),                           \
        "=&v"(k0), "=&v"(k1), "=&v"(k2), "=&v"(k3)                            \
      : "v"(a0_), "v"(a1_), "v"(a2_), "v"(a3_), "v"(kptr)                     \
      : "memory");                                                            \
    MACLO(L0, L1, L2, L3, L4, k0);  MACHI(L4, L5, L6, L7, L8, k0);            \
    MACLO(L1, L2, L3, L4, L5, k1);  MACHI(L5, L6, L7, L8, L9, k1);            \
    MACLO(L2, L3, L4, L5, L6, k2);  MACHI(L6, L7, L8, L9, L10, k2);           \
    MACLO(L3, L4, L5, L6, L7, k3);  MACHI(L7, L8, L9, L10, L11, k3);          \
    gnext += 4; kptr += 64;                                                   \
  } while (0)

__global__ __launch_bounds__(128, 4) void corr_topk_kernel(
    const float* __restrict__ Q, const float* __restrict__ K,
    float* __restrict__ ws_w, int* __restrict__ ws_i)
{
  __shared__ __align__(16) float qs[8][576];   // 18432 B, additive pad
  __shared__ __align__(16) float ks[8][512];   // 16384 B, linear (34816 B)

  const int tid = threadIdx.x;
  const int bid = blockIdx.x;
  const int work = (bid & 7) * 1024 + (bid >> 3);   // XCD chunking
  const int bh   = work >> 6;
  const int c0   = (work & 63) * 8;

  const size_t base = (size_t)(bh >> 3) * (size_t)(L_LEN * D_DIM)
                    + (size_t)(bh & 7) * 512 + c0;

  #pragma unroll
  for (int rep = 0; rep < 8; ++rep) {
    const int idx  = rep * 128 + tid;       // 0..1023
    const int t    = idx >> 1;
    const int half = idx & 1;
    const float4 qv = *(const float4*)(Q + base + (size_t)t * D_DIM + half * 4);
    const float4 kv = *(const float4*)(K + base + (size_t)t * D_DIM + half * 4);
    const int g  = t >> 2;
    const int pw = ((g + (g >> 3)) << 2) | (t & 3);
    const int cb = half * 4;
    const float qa[4] = {qv.x, qv.y, qv.z, qv.w};
    const float ka[4] = {kv.x, kv.y, kv.z, kv.w};
    #pragma unroll
    for (int j = 0; j < 4; ++j) {
      qs[cb + j][pw] = qa[j];
      ks[cb + j][t]  = ka[j];
    }
  }
  __syncthreads();

  const int wv   = tid >> 6;                // 0..1
  const int lane = tid & 63;
  const int m    = lane & 15;               // tau index within channel
  const int ch   = wv * 4 + (lane >> 4);    // channel of this 16-lane group
  const int tau0 = m * 32;
  const uint32_t gq = (uint32_t)(m * 8);

  const uint32_t qbase = (uint32_t)(uintptr_t)(&qs[ch][0]);
  uint32_t       kptr  = (uint32_t)(uintptr_t)(&ks[ch][0]);

  float acc0  = 0.f, acc1  = 0.f, acc2  = 0.f, acc3  = 0.f;
  float acc4  = 0.f, acc5  = 0.f, acc6  = 0.f, acc7  = 0.f;
  float acc8  = 0.f, acc9  = 0.f, acc10 = 0.f, acc11 = 0.f;
  float acc12 = 0.f, acc13 = 0.f, acc14 = 0.f, acc15 = 0.f;
  float acc16 = 0.f, acc17 = 0.f, acc18 = 0.f, acc19 = 0.f;
  float acc20 = 0.f, acc21 = 0.f, acc22 = 0.f, acc23 = 0.f;
  float acc24 = 0.f, acc25 = 0.f, acc26 = 0.f, acc27 = 0.f;
  float acc28 = 0.f, acc29 = 0.f, acc30 = 0.f, acc31 = 0.f;
  f32x4 A0, A1, A2, A3, B0, B1, B2, B3, C0, C1, C2, C3, D0, D1, D2, D3;
  f32x4 k0, k1, k2, k3;

  // prologue: 12 window quads (groups gq..gq+11) + step-0 k
  {
    const uint32_t p0 = QA(gq),      p1 = QA(gq + 1);
    const uint32_t p2 = QA(gq + 2),  p3 = QA(gq + 3);
    const uint32_t p4 = QA(gq + 4),  p5 = QA(gq + 5);
    const uint32_t p6 = QA(gq + 6),  p7 = QA(gq + 7);
    const uint32_t p8 = QA(gq + 8),  p9 = QA(gq + 9);
    const uint32_t pa = QA(gq + 10), pb = QA(gq + 11);
    asm volatile(
      "ds_read_b128 %0, %12\n\t"
      "ds_read_b128 %1, %13\n\t"
      "ds_read_b128 %2, %14\n\t"
      "ds_read_b128 %3, %15\n\t"
      "ds_read_b128 %4, %16\n\t"
      "ds_read_b128 %5, %17\n\t"
      "ds_read_b128 %6, %18\n\t"
      "ds_read_b128 %7, %19\n\t"
      "ds_read_b128 %8, %20\n\t"
      "ds_read_b128 %9, %21\n\t"
      "ds_read_b128 %10, %22\n\t"
      "ds_read_b128 %11, %23"
      : "=&v"(A0), "=&v"(A1), "=&v"(A2), "=&v"(A3),
        "=&v"(B0), "=&v"(B1), "=&v"(B2), "=&v"(B3),
        "=&v"(C0), "=&v"(C1), "=&v"(C2), "=&v"(C3)
      : "v"(p0), "v"(p1), "v"(p2), "v"(p3), "v"(p4), "v"(p5),
        "v"(p6), "v"(p7), "v"(p8), "v"(p9), "v"(pa), "v"(pb)
      : "memory");
    asm volatile(
      "ds_read_b128 %0, %4\n\t"
      "ds_read_b128 %1, %4 offset:16\n\t"
      "ds_read_b128 %2, %4 offset:32\n\t"
      "ds_read_b128 %3, %4 offset:48\n\t"
      "s_waitcnt lgkmcnt(0)"
      : "=&v"(k0), "=&v"(k1), "=&v"(k2), "=&v"(k3)
      : "v"(kptr)
      : "memory");
  }
  // NOTE: first ITER32 re-reads k for step 0? No — schedule below: step 0's
  // k is already in k0..k3, so step 0 does MACs first then the macro shape
  // wouldn't fit. Simplest correct schedule: let ITER32 always load its own
  // k; prologue k regs above are ONLY to initialize names (avoid -Wuninit).
  // kptr still points at step 0's k: ITER32 #0 re-reads the same data.

  uint32_t gnext = gq + 12;

  // 32 steps, period-4 bank rotation; step 31 refills junk (unused)
  #pragma unroll 1
  for (int it = 0; it < 8; ++it) {
    ITER32(A0,A1,A2,A3, B0,B1,B2,B3, C0,C1,C2,C3, D0,D1,D2,D3);
    ITER32(B0,B1,B2,B3, C0,C1,C2,C3, D0,D1,D2,D3, A0,A1,A2,A3);
    ITER32(C0,C1,C2,C3, D0,D1,D2,D3, A0,A1,A2,A3, B0,B1,B2,B3);
    ITER32(D0,D1,D2,D3, A0,A1,A2,A3, B0,B1,B2,B3, C0,C1,C2,C3);
  }

  float acc[32] = {acc0,  acc1,  acc2,  acc3,  acc4,  acc5,  acc6,  acc7,
                   acc8,  acc9,  acc10, acc11, acc12, acc13, acc14, acc15,
                   acc16, acc17, acc18, acc19, acc20, acc21, acc22, acc23,
                   acc24, acc25, acc26, acc27, acc28, acc29, acc30, acc31};

  // top-12 via repeated argmax over the 16-lane channel group
  float bv[TOPK]; int bi[TOPK];
  #pragma unroll
  for (int s = 0; s < TOPK; ++s) {
    float lv = acc[0]; int li = 0;
    #pragma unroll
    for (int i = 1; i < 32; ++i) if (acc[i] > lv) { lv = acc[i]; li = i; }
    int gi = tau0 + li;
    #pragma unroll
    for (int off = 8; off >= 1; off >>= 1) {
      const float ov = __shfl_xor(lv, off, 16);
      const int   oi = __shfl_xor(gi, off, 16);
      if (ov > lv || (ov == lv && oi < gi)) { lv = ov; gi = oi; }
    }
    bv[s] = lv; bi[s] = gi;
    const int slot = gi - tau0;
    #pragma unroll
    for (int i = 0; i < 32; ++i) acc[i] = (slot == i) ? -3.4e38f : acc[i];
  }

  float e[TOPK]; float sum = 0.f;
  #pragma unroll
  for (int s = 0; s < TOPK; ++s) { e[s] = expf(bv[s] - bv[0]); sum += e[s]; }
  const float inv = 1.f / sum;

  if (m == 0) {
    const int g = (bh * 512 + c0 + ch) * TOPK;
    #pragma unroll
    for (int s = 0; s < TOPK; ++s) { ws_w[g + s] = e[s] * inv; ws_i[g + s] = bi[s]; }
  }
}

// ---------------------------------------------------------------------------
// Stage B — 16-col tiles + dup row 512 (= row 511) so each thread computes
// TWO consecutive t with vs[r][cl] / vs[r+1][cl] from the SAME base ->
// compiler fuses to ds_read2_b32 (halves LDS instructions; clamp-correct:
// r>=511 -> ra=511, ra+1=512=dup). vs[513][16] = 32832 B -> 4 blocks/CU.
// Descending quarters, 1 raw s_barrier/phase, prefetch in VMEM flight.
// grid = 16 b * 256 dg = 4096 blocks of 512 threads (launch line verified
// against indexing: work in [0,4096), b in [0,16), dg in [0,256)).
// ---------------------------------------------------------------------------
__global__ __launch_bounds__(512, 8) void gather_kernel(
    const float* __restrict__ V, const float* __restrict__ ws_w,
    const int* __restrict__ ws_i, float* __restrict__ out)
{
  __shared__ __align__(16) float vs[513][16];   // 32832 B; row 512 dups 511

  const int tid = threadIdx.x;
  const int bid = blockIdx.x;
  const int work = (bid & 7) * 512 + (bid >> 3);   // 4096 = 8 * 512
  const int b  = work >> 8;
  const int dg = work & 255;
  const int d0 = dg * 16;
  const int h  = d0 >> 9;
  const int c0 = d0 & 511;

  const size_t vcol = (size_t)b * (size_t)(L_LEN * D_DIM) + d0;

  const int cl = tid & 15;
  const int tp = tid >> 4;                // 0..31: t-pair index

  const int ra = tid >> 2;                // row 0..127 within quarter
  const int qa = (tid & 3) * 4;           // 0,4,8,12

  float4 stga;
  stga = *(const float4*)(V + vcol + (size_t)(384 + ra) * D_DIM + qa);

  const int g = ((b * 8 + h) * 512 + c0 + cl) * TOPK;
  float w[TOPK]; int r0[TOPK];
  #pragma unroll
  for (int s = 0; s < TOPK; ++s) { w[s] = ws_w[g + s]; r0[s] = ws_i[g + s]; }

  const size_t ob = vcol + cl;

  #pragma unroll 1
  for (int ph = 3; ph >= 0; --ph) {
    *(float4*)(&vs[ph * 128 + ra][qa]) = stga;    // vmcnt auto-waited
    if (ph == 3 && ra == 127)                     // dup row 512 <- row 511
      *(float4*)(&vs[512][qa]) = stga;
    if (ph > 0) {
      stga = *(const float4*)(V + vcol + (size_t)((ph - 1) * 128 + ra) * D_DIM + qa);
    }
    asm volatile("s_waitcnt lgkmcnt(0)" ::: "memory");
    __builtin_amdgcn_s_barrier();
    asm volatile("" ::: "memory");

    // outputs t in [ph*128,(ph+1)*128): 2 pairs of consecutive t per thread
    #pragma unroll
    for (int j = 0; j < 2; ++j) {
      const int tb = ph * 128 + j * 64 + tp * 2;
      float a0 = 0.f, a1 = 0.f;
      #pragma unroll
      for (int s = 0; s < TOPK; ++s) {
        int r = r0[s] + tb;
        r = r > (L_LEN - 1) ? (L_LEN - 1) : r;
        const float v0 = vs[r][cl];
        const float v1 = vs[r + 1][cl];   // same base +64B -> ds_read2_b32
        a0 = fmaf(w[s], v0, a0);
        a1 = fmaf(w[s], v1, a1);
      }
      out[ob + (size_t)tb * D_DIM]       = a0;
      out[ob + (size_t)(tb + 1) * D_DIM] = a1;
    }
  }
}

extern "C" void kernel_launch(void* const* d_in, const int* in_sizes, int n_in,
                              void* d_out, int out_size, void* d_ws, size_t ws_size,
                              hipStream_t stream)
{
  const float* Q = (const float*)d_in[0];
  const float* K = (const float*)d_in[1];
  const float* V = (const float*)d_in[2];
  float* out = (float*)d_out;

  float* ws_w = (float*)d_ws;
  int*   ws_i = (int*)((char*)d_ws + (size_t)B_NUM * H_NUM * 512 * TOPK * sizeof(float));

  corr_topk_kernel<<<dim3(B_NUM * H_NUM * 64), dim3(128), 0, stream>>>(Q, K, ws_w, ws_i);
  gather_kernel<<<dim3(B_NUM * 256), dim3(512), 0, stream>>>(V, ws_w, ws_i, out);
}